// Round 18
// baseline (77.589 us; speedup 1.0000x reference)
//
#include <hip/hip_runtime.h>
#include <math.h>

#define BB 4
#define NN 2048
#define CIN 64
#define HID 128
#define HEADS 4
#define NQ 16
#define KTOT (NN*HID) // 262144
#define LOG2E 1.44269504088896340736f
#define NEGBIG_BITS 0xC2C80000u   // -100.0f
#define NSL 8         // j-slices (256 j each)

typedef __attribute__((ext_vector_type(8))) _Float16 half8;
typedef __attribute__((ext_vector_type(4))) float f32x4;
typedef __attribute__((ext_vector_type(4))) unsigned uint4v;

// ---------------- k_hidden: h = x@W_in + b -> TILED hHT[b][jblk][d][j32], alphas ---------
__global__ __launch_bounds__(256) void k_hidden(
    const float* __restrict__ x, const float* __restrict__ W_in,
    const float* __restrict__ b_in, const float* __restrict__ att_src,
    const float* __restrict__ att_dst, _Float16* __restrict__ hHT,
    float* __restrict__ srcA, float* __restrict__ dstA)
{
    __shared__ float Wl[CIN * HID];   // 32 KB
    __shared__ float xl[16][CIN];     // 4 KB
    const int t = threadIdx.x;
    const int jj0 = blockIdx.x * 16;

    {
        const float4* Ws = (const float4*)W_in;
        float4* Wd = (float4*)Wl;
#pragma unroll
        for (int u = 0; u < 8; ++u) Wd[t + 256 * u] = Ws[t + 256 * u];
        ((float4*)&xl[0][0])[t] = ((const float4*)(x + (size_t)jj0 * CIN))[t];
    }
    __syncthreads();

    const int c = t & 127, rg = t >> 7;
    const int b = jj0 >> 11, j0 = (jj0 & (NN - 1)) + rg * 8;
    const int h = c >> 5;

    float acc[8];
    const float bc = b_in[c];
#pragma unroll
    for (int rr = 0; rr < 8; ++rr) acc[rr] = bc;

#pragma unroll
    for (int k4 = 0; k4 < CIN; k4 += 4) {
        const float w0 = Wl[(k4 + 0) * HID + c];
        const float w1 = Wl[(k4 + 1) * HID + c];
        const float w2 = Wl[(k4 + 2) * HID + c];
        const float w3 = Wl[(k4 + 3) * HID + c];
#pragma unroll
        for (int rr = 0; rr < 8; ++rr) {
            const float4 xv = *(const float4*)&xl[rg * 8 + rr][k4];
            acc[rr] = fmaf(xv.w, w3, fmaf(xv.z, w2, fmaf(xv.y, w1, fmaf(xv.x, w0, acc[rr]))));
        }
    }

    half8 hv;
#pragma unroll
    for (int rr = 0; rr < 8; ++rr) hv[rr] = (_Float16)acc[rr];
    // tiled store: [b][jblk=j0>>5][d=c][j0&31 .. +8)
    *(half8*)(hHT + (size_t)b * KTOT + (size_t)(j0 >> 5) * 4096 + c * 32 + (j0 & 31)) = hv;

    const float as = att_src[c], ad = att_dst[c];
#pragma unroll
    for (int rr = 0; rr < 8; ++rr) {
        float vs = acc[rr] * as, vd = acc[rr] * ad;
#pragma unroll
        for (int m = 16; m >= 1; m >>= 1) {
            vs += __shfl_xor(vs, m, 64);
            vd += __shfl_xor(vd, m, 64);
        }
        if ((t & 31) == 0) {
            srcA[(size_t)(b * HEADS + h) * NN + j0 + rr] = vs * LOG2E;
            dstA[(size_t)(b * HEADS + h) * NN + j0 + rr] = vd * LOG2E;
        }
    }
}

// ---------------- k_adjb: adj -> TRANSPOSED bitmask adjT[jw][i]; block 0 inits out -------
__global__ __launch_bounds__(256) void k_adjb(const int* __restrict__ adj,
                                              unsigned* __restrict__ adjT,
                                              const float* __restrict__ b_out,
                                              float* __restrict__ dout)
{
    const int t = threadIdx.x;
    if (blockIdx.x == 0 && t < 64) dout[t] = b_out[t & 15];
    const int gid = blockIdx.x * 256 + t;              // 0 .. N*N/8-1
    const int lane = t & 63;
    const int4* p = (const int4*)(adj + (size_t)gid * 8);
    const int4 a = p[0], b = p[1];
    unsigned byte =
        (a.x != 0 ? 1u : 0u)  | (a.y != 0 ? 2u : 0u)  | (a.z != 0 ? 4u : 0u)  | (a.w != 0 ? 8u : 0u) |
        (b.x != 0 ? 16u : 0u) | (b.y != 0 ? 32u : 0u) | (b.z != 0 ? 64u : 0u) | (b.w != 0 ? 128u : 0u);
    unsigned u = byte | (((unsigned)__shfl_xor((int)byte, 1, 64)) << 8);
    u = u | (((unsigned)__shfl_xor((int)u, 2, 64)) << 16);
    if ((lane & 3) == 0) {
        const int widx = gid >> 2;                     // = i*64 + jw
        const int i = widx >> 6, jw = widx & 63;
        adjT[(size_t)jw * NN + i] = u;                 // transposed
    }
}

// ---------------- k_attn: register flash-GAT, i-tile 32, NSL=8 for occupancy ------------
// grid 2048 x 256 thr; block = (iq 64, b 4, jq 8); 4 waves = 4 heads.
// Wave: 32 i-rows (2 A-frags) x 256 j; per iter 6 coalesced loads vs ~350 cyc compute.
__global__ __launch_bounds__(256, 5) void k_attn(
    const unsigned* __restrict__ adjT, const _Float16* __restrict__ hHT,
    const float* __restrict__ srcA, const float* __restrict__ dstA,
    float* __restrict__ P, float* __restrict__ S)
{
    const int t = threadIdx.x;
    const int lane = t & 63;
    const int h = t >> 6;                // wave id = head
    const int bx = blockIdx.x;
    const int iq = bx & 63;
    const int b = (bx >> 6) & 3;
    const int jq = bx >> 8;              // 0..7
    const int i0 = iq * 32;
    const int jb0 = jq * 8;              // first 32-j block of this wave's 256-j slice

    const int r16 = lane & 15;
    const int g = lane >> 4;

    const float srci0 = srcA[(size_t)(b * HEADS + h) * NN + i0 + r16];
    const float srci1 = srcA[(size_t)(b * HEADS + h) * NN + i0 + 16 + r16];
    const unsigned* adjr0 = adjT + (size_t)jb0 * NN + i0 + r16;                // +n*NN
    const unsigned* adjr1 = adjr0 + 16;
    const _Float16* hb = hHT + (size_t)b * KTOT + (size_t)jb0 * 4096
                             + (h * 32 + r16) * 32 + g * 8;                    // +n*4096
    const float4* dst4 = (const float4*)(dstA + (size_t)(b * HEADS + h) * NN + jq * 256) + 2 * g;

    f32x4 acc00 = {0.f, 0.f, 0.f, 0.f};   // frag0 (i0..i0+15), d lo16
    f32x4 acc01 = {0.f, 0.f, 0.f, 0.f};   // frag0, d hi16
    f32x4 acc10 = {0.f, 0.f, 0.f, 0.f};   // frag1 (i0+16..31), d lo16
    f32x4 acc11 = {0.f, 0.f, 0.f, 0.f};   // frag1, d hi16
    f32x4 accS0 = {0.f, 0.f, 0.f, 0.f};
    f32x4 accS1 = {0.f, 0.f, 0.f, 0.f};
    const half8 ones = {(_Float16)1.f, (_Float16)1.f, (_Float16)1.f, (_Float16)1.f,
                        (_Float16)1.f, (_Float16)1.f, (_Float16)1.f, (_Float16)1.f};

    // weights for one i-frag from adj bits + dst values (log2-scaled)
    auto MAKEAF = [&](float srci, unsigned bits, const float* dvv) -> half8 {
        float wv[8];
#pragma unroll
        for (int e = 0; e < 8; ++e) {
            float s = srci + dvv[e];
            s = fmaxf(s, 0.2f * s);                                   // leaky relu
            const unsigned m = (unsigned)(((int)(bits << (31 - e))) >> 31);
            const unsigned su = __builtin_bit_cast(unsigned, s);
            wv[e] = __builtin_amdgcn_exp2f(
                __builtin_bit_cast(float, (su & m) | (NEGBIG_BITS & ~m)));
        }
        uint4v uu;
        uu[0] = __builtin_bit_cast(unsigned, __builtin_amdgcn_cvt_pkrtz(wv[0], wv[1]));
        uu[1] = __builtin_bit_cast(unsigned, __builtin_amdgcn_cvt_pkrtz(wv[2], wv[3]));
        uu[2] = __builtin_bit_cast(unsigned, __builtin_amdgcn_cvt_pkrtz(wv[4], wv[5]));
        uu[3] = __builtin_bit_cast(unsigned, __builtin_amdgcn_cvt_pkrtz(wv[6], wv[7]));
        return __builtin_bit_cast(half8, uu);
    };

#pragma unroll 1
    for (int n = 0; n < 8; ++n) {
        const unsigned w0 = adjr0[(size_t)n * NN];           // 64B coalesced
        const unsigned w1 = adjr1[(size_t)n * NN];           // 64B coalesced
        const half8 bb0 = *(const half8*)(hb + n * 4096);        // 1KB coalesced (d lo16)
        const half8 bb1 = *(const half8*)(hb + n * 4096 + 512);  // 1KB coalesced (d hi16)
        const float4 dv0 = dst4[n * 8];                          // broadcast
        const float4 dv1 = dst4[n * 8 + 1];
        __builtin_amdgcn_sched_barrier(0);                   // keep load cluster intact

        const float dvv[8] = {dv0.x, dv0.y, dv0.z, dv0.w, dv1.x, dv1.y, dv1.z, dv1.w};
        const half8 af0 = MAKEAF(srci0, w0 >> (8 * g), dvv);
        const half8 af1 = MAKEAF(srci1, w1 >> (8 * g), dvv);
        acc00 = __builtin_amdgcn_mfma_f32_16x16x32_f16(af0, bb0, acc00, 0, 0, 0);
        acc01 = __builtin_amdgcn_mfma_f32_16x16x32_f16(af0, bb1, acc01, 0, 0, 0);
        accS0 = __builtin_amdgcn_mfma_f32_16x16x32_f16(af0, ones, accS0, 0, 0, 0);
        acc10 = __builtin_amdgcn_mfma_f32_16x16x32_f16(af1, bb0, acc10, 0, 0, 0);
        acc11 = __builtin_amdgcn_mfma_f32_16x16x32_f16(af1, bb1, acc11, 0, 0, 0);
        accS1 = __builtin_amdgcn_mfma_f32_16x16x32_f16(af1, ones, accS1, 0, 0, 0);
    }

    // direct store of both frags (verified layout: i = 4g+r, d = r16)
    const size_t prow0 = (size_t)(jq * BB + b) * NN + i0;
#pragma unroll
    for (int r = 0; r < 4; ++r) {
        const size_t row0 = prow0 + 4 * g + r;
        const size_t row1 = prow0 + 16 + 4 * g + r;
        P[row0 * HID + h * 32 + r16]      = acc00[r];
        P[row0 * HID + h * 32 + 16 + r16] = acc01[r];
        P[row1 * HID + h * 32 + r16]      = acc10[r];
        P[row1 * HID + h * 32 + 16 + r16] = acc11[r];
        if (r16 == 0) {
            S[row0 * HEADS + h] = accS0[r];
            S[row1 * HEADS + h] = accS1[r];
        }
    }
}

// ---------------- k_proj: combine 8 f32 partials + projection (W^T in LDS) --------------
__global__ __launch_bounds__(256) void k_proj(
    const float* __restrict__ P, const float* __restrict__ S,
    const float* __restrict__ W_out, float* __restrict__ dout)
{
    __shared__ float wlT[NQ][260];     // 16.6 KB
    __shared__ float red[256];

    const int t = threadIdx.x;
    const int k0 = blockIdx.x * 256;

#pragma unroll
    for (int u = 0; u < 4; ++u) {
        const int flat = (u * 256 + t) * 4;
        const float4 wv = *(const float4*)(W_out + (size_t)k0 * NQ + flat);
        const int krel = flat >> 4;
        const int q0 = flat & 15;
        wlT[q0 + 0][krel] = wv.x;
        wlT[q0 + 1][krel] = wv.y;
        wlT[q0 + 2][krel] = wv.z;
        wlT[q0 + 3][krel] = wv.w;
    }
    __syncthreads();

    const int q = t & 15;
    const int b = (t >> 4) & 3;
    const int ks = (t >> 6) * 64;
    const int i = (k0 + ks) >> 7;

    const float* p0 = P + (size_t)(0 * BB + b) * KTOT + k0 + ks;
    const float* p1 = P + (size_t)(1 * BB + b) * KTOT + k0 + ks;
    const float* p2 = P + (size_t)(2 * BB + b) * KTOT + k0 + ks;
    const float* p3 = P + (size_t)(3 * BB + b) * KTOT + k0 + ks;
    const float* p4 = P + (size_t)(4 * BB + b) * KTOT + k0 + ks;
    const float* p5 = P + (size_t)(5 * BB + b) * KTOT + k0 + ks;
    const float* p6 = P + (size_t)(6 * BB + b) * KTOT + k0 + ks;
    const float* p7 = P + (size_t)(7 * BB + b) * KTOT + k0 + ks;

    float acc = 0.f;
#pragma unroll
    for (int seg = 0; seg < 2; ++seg) {
        const int h = ((k0 + ks + seg * 32) >> 5) & 3;
        float rs = 0.f;
#pragma unroll
        for (int s = 0; s < NSL; ++s)
            rs += S[((size_t)(s * BB + b) * NN + i) * HEADS + h];
        const float inv = __builtin_amdgcn_rcpf(rs);
#pragma unroll
        for (int k4 = 0; k4 < 8; ++k4) {
            const int kk = seg * 32 + k4 * 4;
            const float4 a0 = *(const float4*)(p0 + kk);
            const float4 a1 = *(const float4*)(p1 + kk);
            const float4 a2 = *(const float4*)(p2 + kk);
            const float4 a3 = *(const float4*)(p3 + kk);
            const float4 a4 = *(const float4*)(p4 + kk);
            const float4 a5 = *(const float4*)(p5 + kk);
            const float4 a6 = *(const float4*)(p6 + kk);
            const float4 a7 = *(const float4*)(p7 + kk);
            const float4 wq = *(const float4*)&wlT[q][ks + kk];
            const float ex = ((a0.x + a1.x) + (a2.x + a3.x)) + ((a4.x + a5.x) + (a6.x + a7.x));
            const float ey = ((a0.y + a1.y) + (a2.y + a3.y)) + ((a4.y + a5.y) + (a6.y + a7.y));
            const float ez = ((a0.z + a1.z) + (a2.z + a3.z)) + ((a4.z + a5.z) + (a6.z + a7.z));
            const float ew = ((a0.w + a1.w) + (a2.w + a3.w)) + ((a4.w + a5.w) + (a6.w + a7.w));
            acc = fmaf(ex * inv, wq.x, acc);
            acc = fmaf(ey * inv, wq.y, acc);
            acc = fmaf(ez * inv, wq.z, acc);
            acc = fmaf(ew * inv, wq.w, acc);
        }
    }

    red[t] = acc;
    __syncthreads();
    if (t < 64)
        atomicAdd(&dout[t], red[t] + red[t + 64] + red[t + 128] + red[t + 192]);
}

extern "C" void kernel_launch(void* const* d_in, const int* in_sizes, int n_in,
                              void* d_out, int out_size, void* d_ws, size_t ws_size,
                              hipStream_t stream)
{
    const float* x       = (const float*)d_in[0];
    const int*   adj     = (const int*)d_in[1];
    const float* W_in    = (const float*)d_in[2];
    const float* b_in    = (const float*)d_in[3];
    const float* att_src = (const float*)d_in[4];
    const float* att_dst = (const float*)d_in[5];
    const float* W_out   = (const float*)d_in[6];
    const float* b_out   = (const float*)d_in[7];
    float* out = (float*)d_out;

    float* P    = (float*)d_ws;                              // NSL*BB*KTOT f32 = 33.6 MB
    float* S    = P + (size_t)NSL * BB * KTOT;               // 1 MB
    float* srcA = S + (size_t)NSL * BB * NN * HEADS;         // 128 KB
    float* dstA = srcA + (size_t)BB * HEADS * NN;            // 128 KB
    _Float16* hHT = (_Float16*)(dstA + (size_t)BB * HEADS * NN);          // 2 MB (tiled)
    unsigned* adjT = (unsigned*)((char*)hHT + sizeof(_Float16) * (size_t)BB * KTOT); // 512 KB

    k_hidden<<<BB * NN / 16, 256, 0, stream>>>(x, W_in, b_in, att_src, att_dst, hHT, srcA, dstA);
    k_adjb<<<NN * NN / 8 / 256, 256, 0, stream>>>(adj, adjT, b_out, out);
    // block = (iq 64, b 4, jq 8) -> 2048 blocks x 4 waves = 8192 waves
    k_attn<<<NSL * BB * (NN / 32), 256, 0, stream>>>(adjT, hHT, srcA, dstA, P, S);
    k_proj<<<KTOT / 256, 256, 0, stream>>>(P, S, W_out, out);
}

// Round 19
// 73.502 us; speedup vs baseline: 1.0556x; 1.0556x over previous
//
#include <hip/hip_runtime.h>
#include <math.h>

#define BB 4
#define NN 2048
#define CIN 64
#define HID 128
#define HEADS 4
#define NQ 16
#define KTOT (NN*HID) // 262144
#define LOG2E 1.44269504088896340736f
#define NEGBIG_BITS 0xC2C80000u   // -100.0f
#define NSL 4         // j-slices (512 j each)

typedef __attribute__((ext_vector_type(8))) _Float16 half8;
typedef __attribute__((ext_vector_type(4))) float f32x4;
typedef __attribute__((ext_vector_type(4))) unsigned uint4v;

// ---------------- k_hidden: h = x@W_in + b -> TILED hHT[b][jblk][d][j32], alphas ---------
__global__ __launch_bounds__(256) void k_hidden(
    const float* __restrict__ x, const float* __restrict__ W_in,
    const float* __restrict__ b_in, const float* __restrict__ att_src,
    const float* __restrict__ att_dst, _Float16* __restrict__ hHT,
    float* __restrict__ srcA, float* __restrict__ dstA)
{
    __shared__ float Wl[CIN * HID];   // 32 KB
    __shared__ float xl[16][CIN];     // 4 KB
    const int t = threadIdx.x;
    const int jj0 = blockIdx.x * 16;

    {
        const float4* Ws = (const float4*)W_in;
        float4* Wd = (float4*)Wl;
#pragma unroll
        for (int u = 0; u < 8; ++u) Wd[t + 256 * u] = Ws[t + 256 * u];
        ((float4*)&xl[0][0])[t] = ((const float4*)(x + (size_t)jj0 * CIN))[t];
    }
    __syncthreads();

    const int c = t & 127, rg = t >> 7;
    const int b = jj0 >> 11, j0 = (jj0 & (NN - 1)) + rg * 8;
    const int h = c >> 5;

    float acc[8];
    const float bc = b_in[c];
#pragma unroll
    for (int rr = 0; rr < 8; ++rr) acc[rr] = bc;

#pragma unroll
    for (int k4 = 0; k4 < CIN; k4 += 4) {
        const float w0 = Wl[(k4 + 0) * HID + c];
        const float w1 = Wl[(k4 + 1) * HID + c];
        const float w2 = Wl[(k4 + 2) * HID + c];
        const float w3 = Wl[(k4 + 3) * HID + c];
#pragma unroll
        for (int rr = 0; rr < 8; ++rr) {
            const float4 xv = *(const float4*)&xl[rg * 8 + rr][k4];
            acc[rr] = fmaf(xv.w, w3, fmaf(xv.z, w2, fmaf(xv.y, w1, fmaf(xv.x, w0, acc[rr]))));
        }
    }

    half8 hv;
#pragma unroll
    for (int rr = 0; rr < 8; ++rr) hv[rr] = (_Float16)acc[rr];
    // tiled store: [b][jblk=j0>>5][d=c][j0&31 .. +8)
    *(half8*)(hHT + (size_t)b * KTOT + (size_t)(j0 >> 5) * 4096 + c * 32 + (j0 & 31)) = hv;

    const float as = att_src[c], ad = att_dst[c];
#pragma unroll
    for (int rr = 0; rr < 8; ++rr) {
        float vs = acc[rr] * as, vd = acc[rr] * ad;
#pragma unroll
        for (int m = 16; m >= 1; m >>= 1) {
            vs += __shfl_xor(vs, m, 64);
            vd += __shfl_xor(vd, m, 64);
        }
        if ((t & 31) == 0) {
            srcA[(size_t)(b * HEADS + h) * NN + j0 + rr] = vs * LOG2E;
            dstA[(size_t)(b * HEADS + h) * NN + j0 + rr] = vd * LOG2E;
        }
    }
}

// ---------------- k_adjb: adj -> TRANSPOSED bitmask adjT[jw][i]; block 0 inits out -------
__global__ __launch_bounds__(256) void k_adjb(const int* __restrict__ adj,
                                              unsigned* __restrict__ adjT,
                                              const float* __restrict__ b_out,
                                              float* __restrict__ dout)
{
    const int t = threadIdx.x;
    if (blockIdx.x == 0 && t < 64) dout[t] = b_out[t & 15];
    const int gid = blockIdx.x * 256 + t;              // 0 .. N*N/8-1
    const int lane = t & 63;
    const int4* p = (const int4*)(adj + (size_t)gid * 8);
    const int4 a = p[0], b = p[1];
    unsigned byte =
        (a.x != 0 ? 1u : 0u)  | (a.y != 0 ? 2u : 0u)  | (a.z != 0 ? 4u : 0u)  | (a.w != 0 ? 8u : 0u) |
        (b.x != 0 ? 16u : 0u) | (b.y != 0 ? 32u : 0u) | (b.z != 0 ? 64u : 0u) | (b.w != 0 ? 128u : 0u);
    unsigned u = byte | (((unsigned)__shfl_xor((int)byte, 1, 64)) << 8);
    u = u | (((unsigned)__shfl_xor((int)u, 2, 64)) << 16);
    if ((lane & 3) == 0) {
        const int widx = gid >> 2;                     // = i*64 + jw
        const int i = widx >> 6, jw = widx & 63;
        adjT[(size_t)jw * NN + i] = u;                 // transposed
    }
}

// ---------------- k_attn: register flash-GAT, i-tile 32, fenced depth-1 prefetch --------
// grid 1024 x 256 thr; block = (iq 64, b 4, jq 4); 4 waves = 4 heads.
// Wave: 32 i-rows (2 A-frags) x 512 j; ping-pong prefetch of next iter's 6 coalesced
// loads, sched_barrier-fenced so the compiler can't sink them (R7 mechanism + R16 layout).
__global__ __launch_bounds__(256, 4) void k_attn(
    const unsigned* __restrict__ adjT, const _Float16* __restrict__ hHT,
    const float* __restrict__ srcA, const float* __restrict__ dstA,
    float* __restrict__ P, float* __restrict__ S)
{
    const int t = threadIdx.x;
    const int lane = t & 63;
    const int h = t >> 6;                // wave id = head
    const int bx = blockIdx.x;
    const int iq = bx & 63;
    const int b = (bx >> 6) & 3;
    const int jq = bx >> 8;
    const int i0 = iq * 32;
    const int jb0 = jq * 16;             // first 32-j block of this wave's 512-j slice

    const int r16 = lane & 15;
    const int g = lane >> 4;

    const float srci0 = srcA[(size_t)(b * HEADS + h) * NN + i0 + r16];
    const float srci1 = srcA[(size_t)(b * HEADS + h) * NN + i0 + 16 + r16];
    const unsigned* adjr0 = adjT + (size_t)jb0 * NN + i0 + r16;                // +n*NN
    const unsigned* adjr1 = adjr0 + 16;
    const _Float16* hb = hHT + (size_t)b * KTOT + (size_t)jb0 * 4096
                             + (h * 32 + r16) * 32 + g * 8;                    // +n*4096
    const float4* dst4 = (const float4*)(dstA + (size_t)(b * HEADS + h) * NN + jq * 512) + 2 * g;

    f32x4 acc00 = {0.f, 0.f, 0.f, 0.f};   // frag0 (i0..i0+15), d lo16
    f32x4 acc01 = {0.f, 0.f, 0.f, 0.f};   // frag0, d hi16
    f32x4 acc10 = {0.f, 0.f, 0.f, 0.f};   // frag1 (i0+16..31), d lo16
    f32x4 acc11 = {0.f, 0.f, 0.f, 0.f};   // frag1, d hi16
    f32x4 accS0 = {0.f, 0.f, 0.f, 0.f};
    f32x4 accS1 = {0.f, 0.f, 0.f, 0.f};
    const half8 ones = {(_Float16)1.f, (_Float16)1.f, (_Float16)1.f, (_Float16)1.f,
                        (_Float16)1.f, (_Float16)1.f, (_Float16)1.f, (_Float16)1.f};

    // weights for one i-frag from adj bits + dst values (log2-scaled)
    auto MAKEAF = [&](float srci, unsigned bits, const float* dvv) -> half8 {
        float wv[8];
#pragma unroll
        for (int e = 0; e < 8; ++e) {
            float s = srci + dvv[e];
            s = fmaxf(s, 0.2f * s);                                   // leaky relu
            const unsigned m = (unsigned)(((int)(bits << (31 - e))) >> 31);
            const unsigned su = __builtin_bit_cast(unsigned, s);
            wv[e] = __builtin_amdgcn_exp2f(
                __builtin_bit_cast(float, (su & m) | (NEGBIG_BITS & ~m)));
        }
        uint4v uu;
        uu[0] = __builtin_bit_cast(unsigned, __builtin_amdgcn_cvt_pkrtz(wv[0], wv[1]));
        uu[1] = __builtin_bit_cast(unsigned, __builtin_amdgcn_cvt_pkrtz(wv[2], wv[3]));
        uu[2] = __builtin_bit_cast(unsigned, __builtin_amdgcn_cvt_pkrtz(wv[4], wv[5]));
        uu[3] = __builtin_bit_cast(unsigned, __builtin_amdgcn_cvt_pkrtz(wv[6], wv[7]));
        return __builtin_bit_cast(half8, uu);
    };

    auto COMPUTE = [&](unsigned w0, unsigned w1, half8 bb0, half8 bb1,
                       float4 dv0, float4 dv1) {
        const float dvv[8] = {dv0.x, dv0.y, dv0.z, dv0.w, dv1.x, dv1.y, dv1.z, dv1.w};
        const half8 af0 = MAKEAF(srci0, w0 >> (8 * g), dvv);
        const half8 af1 = MAKEAF(srci1, w1 >> (8 * g), dvv);
        acc00 = __builtin_amdgcn_mfma_f32_16x16x32_f16(af0, bb0, acc00, 0, 0, 0);
        acc01 = __builtin_amdgcn_mfma_f32_16x16x32_f16(af0, bb1, acc01, 0, 0, 0);
        accS0 = __builtin_amdgcn_mfma_f32_16x16x32_f16(af0, ones, accS0, 0, 0, 0);
        acc10 = __builtin_amdgcn_mfma_f32_16x16x32_f16(af1, bb0, acc10, 0, 0, 0);
        acc11 = __builtin_amdgcn_mfma_f32_16x16x32_f16(af1, bb1, acc11, 0, 0, 0);
        accS1 = __builtin_amdgcn_mfma_f32_16x16x32_f16(af1, ones, accS1, 0, 0, 0);
    };

    // prime buffer A (iteration 0)
    unsigned wA0 = adjr0[0], wA1 = adjr1[0];
    half8 bA0 = *(const half8*)(hb);
    half8 bA1 = *(const half8*)(hb + 512);
    float4 dA0 = dst4[0], dA1 = dst4[1];
    __builtin_amdgcn_sched_barrier(0);

#pragma unroll 1
    for (int p = 0; p < 8; ++p) {
        const int nB = 2 * p + 1;
        // prefetch buffer B (iteration nB) — fenced so it stays here
        const unsigned wB0 = adjr0[(size_t)nB * NN];
        const unsigned wB1 = adjr1[(size_t)nB * NN];
        const half8 bB0 = *(const half8*)(hb + nB * 4096);
        const half8 bB1 = *(const half8*)(hb + nB * 4096 + 512);
        const float4 dB0 = dst4[nB * 8], dB1 = dst4[nB * 8 + 1];
        __builtin_amdgcn_sched_barrier(0);

        COMPUTE(wA0, wA1, bA0, bA1, dA0, dA1);       // iter 2p, B-loads in flight
        __builtin_amdgcn_sched_barrier(0);

        if (p < 7) {                                  // prefetch buffer A (iter 2p+2)
            const int nA = 2 * p + 2;
            wA0 = adjr0[(size_t)nA * NN];
            wA1 = adjr1[(size_t)nA * NN];
            bA0 = *(const half8*)(hb + nA * 4096);
            bA1 = *(const half8*)(hb + nA * 4096 + 512);
            dA0 = dst4[nA * 8]; dA1 = dst4[nA * 8 + 1];
        }
        __builtin_amdgcn_sched_barrier(0);

        COMPUTE(wB0, wB1, bB0, bB1, dB0, dB1);       // iter 2p+1, A-loads in flight
        __builtin_amdgcn_sched_barrier(0);
    }

    // direct store of both frags (verified layout: i = 4g+r, d = r16)
    const size_t prow0 = (size_t)(jq * BB + b) * NN + i0;
#pragma unroll
    for (int r = 0; r < 4; ++r) {
        const size_t row0 = prow0 + 4 * g + r;
        const size_t row1 = prow0 + 16 + 4 * g + r;
        P[row0 * HID + h * 32 + r16]      = acc00[r];
        P[row0 * HID + h * 32 + 16 + r16] = acc01[r];
        P[row1 * HID + h * 32 + r16]      = acc10[r];
        P[row1 * HID + h * 32 + 16 + r16] = acc11[r];
        if (r16 == 0) {
            S[row0 * HEADS + h] = accS0[r];
            S[row1 * HEADS + h] = accS1[r];
        }
    }
}

// ---------------- k_proj: combine 4 f32 partials + projection (W^T in LDS) --------------
__global__ __launch_bounds__(256) void k_proj(
    const float* __restrict__ P, const float* __restrict__ S,
    const float* __restrict__ W_out, float* __restrict__ dout)
{
    __shared__ float wlT[NQ][260];     // 16.6 KB
    __shared__ float red[256];

    const int t = threadIdx.x;
    const int k0 = blockIdx.x * 256;

#pragma unroll
    for (int u = 0; u < 4; ++u) {
        const int flat = (u * 256 + t) * 4;
        const float4 wv = *(const float4*)(W_out + (size_t)k0 * NQ + flat);
        const int krel = flat >> 4;
        const int q0 = flat & 15;
        wlT[q0 + 0][krel] = wv.x;
        wlT[q0 + 1][krel] = wv.y;
        wlT[q0 + 2][krel] = wv.z;
        wlT[q0 + 3][krel] = wv.w;
    }
    __syncthreads();

    const int q = t & 15;
    const int b = (t >> 4) & 3;
    const int ks = (t >> 6) * 64;
    const int i = (k0 + ks) >> 7;

    const float* p0 = P + (size_t)(0 * BB + b) * KTOT + k0 + ks;
    const float* p1 = P + (size_t)(1 * BB + b) * KTOT + k0 + ks;
    const float* p2 = P + (size_t)(2 * BB + b) * KTOT + k0 + ks;
    const float* p3 = P + (size_t)(3 * BB + b) * KTOT + k0 + ks;

    float acc = 0.f;
#pragma unroll
    for (int seg = 0; seg < 2; ++seg) {
        const int h = ((k0 + ks + seg * 32) >> 5) & 3;
        float rs = 0.f;
#pragma unroll
        for (int s = 0; s < NSL; ++s)
            rs += S[((size_t)(s * BB + b) * NN + i) * HEADS + h];
        const float inv = __builtin_amdgcn_rcpf(rs);
#pragma unroll
        for (int k4 = 0; k4 < 8; ++k4) {
            const int kk = seg * 32 + k4 * 4;
            const float4 a0 = *(const float4*)(p0 + kk);
            const float4 a1 = *(const float4*)(p1 + kk);
            const float4 a2 = *(const float4*)(p2 + kk);
            const float4 a3 = *(const float4*)(p3 + kk);
            const float4 wq = *(const float4*)&wlT[q][ks + kk];
            acc = fmaf(((a0.x + a1.x) + (a2.x + a3.x)) * inv, wq.x, acc);
            acc = fmaf(((a0.y + a1.y) + (a2.y + a3.y)) * inv, wq.y, acc);
            acc = fmaf(((a0.z + a1.z) + (a2.z + a3.z)) * inv, wq.z, acc);
            acc = fmaf(((a0.w + a1.w) + (a2.w + a3.w)) * inv, wq.w, acc);
        }
    }

    red[t] = acc;
    __syncthreads();
    if (t < 64)
        atomicAdd(&dout[t], red[t] + red[t + 64] + red[t + 128] + red[t + 192]);
}

extern "C" void kernel_launch(void* const* d_in, const int* in_sizes, int n_in,
                              void* d_out, int out_size, void* d_ws, size_t ws_size,
                              hipStream_t stream)
{
    const float* x       = (const float*)d_in[0];
    const int*   adj     = (const int*)d_in[1];
    const float* W_in    = (const float*)d_in[2];
    const float* b_in    = (const float*)d_in[3];
    const float* att_src = (const float*)d_in[4];
    const float* att_dst = (const float*)d_in[5];
    const float* W_out   = (const float*)d_in[6];
    const float* b_out   = (const float*)d_in[7];
    float* out = (float*)d_out;

    float* P    = (float*)d_ws;                              // NSL*BB*KTOT f32 = 16.8 MB
    float* S    = P + (size_t)NSL * BB * KTOT;               // 512 KB
    float* srcA = S + (size_t)NSL * BB * NN * HEADS;         // 128 KB
    float* dstA = srcA + (size_t)BB * HEADS * NN;            // 128 KB
    _Float16* hHT = (_Float16*)(dstA + (size_t)BB * HEADS * NN);          // 2 MB (tiled)
    unsigned* adjT = (unsigned*)((char*)hHT + sizeof(_Float16) * (size_t)BB * KTOT); // 512 KB

    k_hidden<<<BB * NN / 16, 256, 0, stream>>>(x, W_in, b_in, att_src, att_dst, hHT, srcA, dstA);
    k_adjb<<<NN * NN / 8 / 256, 256, 0, stream>>>(adj, adjT, b_out, out);
    // block = (iq 64, b 4, jq 4) -> 1024 blocks x 4 waves
    k_attn<<<NSL * BB * (NN / 32), 256, 0, stream>>>(adjT, hHT, srcA, dstA, P, S);
    k_proj<<<KTOT / 256, 256, 0, stream>>>(P, S, W_out, out);
}

// Round 20
// 70.710 us; speedup vs baseline: 1.0973x; 1.0395x over previous
//
#include <hip/hip_runtime.h>
#include <math.h>

#define BB 4
#define NN 2048
#define CIN 64
#define HID 128
#define HEADS 4
#define NQ 16
#define KTOT (NN*HID) // 262144
#define LOG2E 1.44269504088896340736f
#define NEGBIG_BITS 0xC2C80000u   // -100.0f
#define NSL 4         // j-slices (512 j each)
#define HB 512        // k_pre blocks doing hidden (16 rows each)
#define AB 2048       // k_pre blocks doing adj bitmask

typedef __attribute__((ext_vector_type(8))) _Float16 half8;
typedef __attribute__((ext_vector_type(4))) float f32x4;
typedef __attribute__((ext_vector_type(4))) unsigned uint4v;

// ---------------- k_pre: hidden GEMM (blocks 0..511) + adj bitmask (blocks 512..2559) ----
// hidden -> TILED hHT[b][jblk][d][j32] f16, alphas pre-scaled log2e; adj -> TRANSPOSED adjT[jw][i].
__global__ __launch_bounds__(256) void k_pre(
    const float* __restrict__ x, const float* __restrict__ W_in,
    const float* __restrict__ b_in, const float* __restrict__ att_src,
    const float* __restrict__ att_dst, const int* __restrict__ adj,
    _Float16* __restrict__ hHT, float* __restrict__ srcA, float* __restrict__ dstA,
    unsigned* __restrict__ adjT, const float* __restrict__ b_out,
    float* __restrict__ dout)
{
    __shared__ float Wl[CIN * HID];   // 32 KB
    __shared__ float xl[16][CIN];     // 4 KB
    const int t = threadIdx.x;

    if (blockIdx.x >= HB) {
        // ---- adj -> transposed bitmask; first adj-block inits d_out ----
        const int bid = blockIdx.x - HB;
        if (bid == 0 && t < 64) dout[t] = b_out[t & 15];
        const int gid = bid * 256 + t;              // 0 .. N*N/8-1
        const int lane = t & 63;
        const int4* p = (const int4*)(adj + (size_t)gid * 8);
        const int4 a = p[0], b = p[1];
        unsigned byte =
            (a.x != 0 ? 1u : 0u)  | (a.y != 0 ? 2u : 0u)  | (a.z != 0 ? 4u : 0u)  | (a.w != 0 ? 8u : 0u) |
            (b.x != 0 ? 16u : 0u) | (b.y != 0 ? 32u : 0u) | (b.z != 0 ? 64u : 0u) | (b.w != 0 ? 128u : 0u);
        unsigned u = byte | (((unsigned)__shfl_xor((int)byte, 1, 64)) << 8);
        u = u | (((unsigned)__shfl_xor((int)u, 2, 64)) << 16);
        if ((lane & 3) == 0) {
            const int widx = gid >> 2;                 // = i*64 + jw
            const int i = widx >> 6, jw = widx & 63;
            adjT[(size_t)jw * NN + i] = u;             // transposed
        }
        return;
    }

    // ---- hidden: 16 rows per block ----
    const int jj0 = blockIdx.x * 16;
    {
        const float4* Ws = (const float4*)W_in;
        float4* Wd = (float4*)Wl;
#pragma unroll
        for (int u = 0; u < 8; ++u) Wd[t + 256 * u] = Ws[t + 256 * u];
        ((float4*)&xl[0][0])[t] = ((const float4*)(x + (size_t)jj0 * CIN))[t];
    }
    __syncthreads();

    const int c = t & 127, rg = t >> 7;
    const int b = jj0 >> 11, j0 = (jj0 & (NN - 1)) + rg * 8;
    const int h = c >> 5;

    float acc[8];
    const float bc = b_in[c];
#pragma unroll
    for (int rr = 0; rr < 8; ++rr) acc[rr] = bc;

#pragma unroll
    for (int k4 = 0; k4 < CIN; k4 += 4) {
        const float w0 = Wl[(k4 + 0) * HID + c];
        const float w1 = Wl[(k4 + 1) * HID + c];
        const float w2 = Wl[(k4 + 2) * HID + c];
        const float w3 = Wl[(k4 + 3) * HID + c];
#pragma unroll
        for (int rr = 0; rr < 8; ++rr) {
            const float4 xv = *(const float4*)&xl[rg * 8 + rr][k4];
            acc[rr] = fmaf(xv.w, w3, fmaf(xv.z, w2, fmaf(xv.y, w1, fmaf(xv.x, w0, acc[rr]))));
        }
    }

    half8 hv;
#pragma unroll
    for (int rr = 0; rr < 8; ++rr) hv[rr] = (_Float16)acc[rr];
    // tiled store: [b][jblk=j0>>5][d=c][j0&31 .. +8)
    *(half8*)(hHT + (size_t)b * KTOT + (size_t)(j0 >> 5) * 4096 + c * 32 + (j0 & 31)) = hv;

    const float as = att_src[c], ad = att_dst[c];
#pragma unroll
    for (int rr = 0; rr < 8; ++rr) {
        float vs = acc[rr] * as, vd = acc[rr] * ad;
#pragma unroll
        for (int m = 16; m >= 1; m >>= 1) {
            vs += __shfl_xor(vs, m, 64);
            vd += __shfl_xor(vd, m, 64);
        }
        if ((t & 31) == 0) {
            srcA[(size_t)(b * HEADS + h) * NN + j0 + rr] = vs * LOG2E;
            dstA[(size_t)(b * HEADS + h) * NN + j0 + rr] = vd * LOG2E;
        }
    }
}

// ---------------- k_attn: register flash-GAT, i-tile 32, fenced depth-1 prefetch --------
// (identical to R19 best config; only the P stores are now f16)
__global__ __launch_bounds__(256, 4) void k_attn(
    const unsigned* __restrict__ adjT, const _Float16* __restrict__ hHT,
    const float* __restrict__ srcA, const float* __restrict__ dstA,
    _Float16* __restrict__ P, float* __restrict__ S)
{
    const int t = threadIdx.x;
    const int lane = t & 63;
    const int h = t >> 6;                // wave id = head
    const int bx = blockIdx.x;
    const int iq = bx & 63;
    const int b = (bx >> 6) & 3;
    const int jq = bx >> 8;
    const int i0 = iq * 32;
    const int jb0 = jq * 16;             // first 32-j block of this wave's 512-j slice

    const int r16 = lane & 15;
    const int g = lane >> 4;

    const float srci0 = srcA[(size_t)(b * HEADS + h) * NN + i0 + r16];
    const float srci1 = srcA[(size_t)(b * HEADS + h) * NN + i0 + 16 + r16];
    const unsigned* adjr0 = adjT + (size_t)jb0 * NN + i0 + r16;                // +n*NN
    const unsigned* adjr1 = adjr0 + 16;
    const _Float16* hb = hHT + (size_t)b * KTOT + (size_t)jb0 * 4096
                             + (h * 32 + r16) * 32 + g * 8;                    // +n*4096
    const float4* dst4 = (const float4*)(dstA + (size_t)(b * HEADS + h) * NN + jq * 512) + 2 * g;

    f32x4 acc00 = {0.f, 0.f, 0.f, 0.f};   // frag0 (i0..i0+15), d lo16
    f32x4 acc01 = {0.f, 0.f, 0.f, 0.f};   // frag0, d hi16
    f32x4 acc10 = {0.f, 0.f, 0.f, 0.f};   // frag1 (i0+16..31), d lo16
    f32x4 acc11 = {0.f, 0.f, 0.f, 0.f};   // frag1, d hi16
    f32x4 accS0 = {0.f, 0.f, 0.f, 0.f};
    f32x4 accS1 = {0.f, 0.f, 0.f, 0.f};
    const half8 ones = {(_Float16)1.f, (_Float16)1.f, (_Float16)1.f, (_Float16)1.f,
                        (_Float16)1.f, (_Float16)1.f, (_Float16)1.f, (_Float16)1.f};

    // weights for one i-frag from adj bits + dst values (log2-scaled)
    auto MAKEAF = [&](float srci, unsigned bits, const float* dvv) -> half8 {
        float wv[8];
#pragma unroll
        for (int e = 0; e < 8; ++e) {
            float s = srci + dvv[e];
            s = fmaxf(s, 0.2f * s);                                   // leaky relu
            const unsigned m = (unsigned)(((int)(bits << (31 - e))) >> 31);
            const unsigned su = __builtin_bit_cast(unsigned, s);
            wv[e] = __builtin_amdgcn_exp2f(
                __builtin_bit_cast(float, (su & m) | (NEGBIG_BITS & ~m)));
        }
        uint4v uu;
        uu[0] = __builtin_bit_cast(unsigned, __builtin_amdgcn_cvt_pkrtz(wv[0], wv[1]));
        uu[1] = __builtin_bit_cast(unsigned, __builtin_amdgcn_cvt_pkrtz(wv[2], wv[3]));
        uu[2] = __builtin_bit_cast(unsigned, __builtin_amdgcn_cvt_pkrtz(wv[4], wv[5]));
        uu[3] = __builtin_bit_cast(unsigned, __builtin_amdgcn_cvt_pkrtz(wv[6], wv[7]));
        return __builtin_bit_cast(half8, uu);
    };

    auto COMPUTE = [&](unsigned w0, unsigned w1, half8 bb0, half8 bb1,
                       float4 dv0, float4 dv1) {
        const float dvv[8] = {dv0.x, dv0.y, dv0.z, dv0.w, dv1.x, dv1.y, dv1.z, dv1.w};
        const half8 af0 = MAKEAF(srci0, w0 >> (8 * g), dvv);
        const half8 af1 = MAKEAF(srci1, w1 >> (8 * g), dvv);
        acc00 = __builtin_amdgcn_mfma_f32_16x16x32_f16(af0, bb0, acc00, 0, 0, 0);
        acc01 = __builtin_amdgcn_mfma_f32_16x16x32_f16(af0, bb1, acc01, 0, 0, 0);
        accS0 = __builtin_amdgcn_mfma_f32_16x16x32_f16(af0, ones, accS0, 0, 0, 0);
        acc10 = __builtin_amdgcn_mfma_f32_16x16x32_f16(af1, bb0, acc10, 0, 0, 0);
        acc11 = __builtin_amdgcn_mfma_f32_16x16x32_f16(af1, bb1, acc11, 0, 0, 0);
        accS1 = __builtin_amdgcn_mfma_f32_16x16x32_f16(af1, ones, accS1, 0, 0, 0);
    };

    // prime buffer A (iteration 0)
    unsigned wA0 = adjr0[0], wA1 = adjr1[0];
    half8 bA0 = *(const half8*)(hb);
    half8 bA1 = *(const half8*)(hb + 512);
    float4 dA0 = dst4[0], dA1 = dst4[1];
    __builtin_amdgcn_sched_barrier(0);

#pragma unroll 1
    for (int p = 0; p < 8; ++p) {
        const int nB = 2 * p + 1;
        // prefetch buffer B (iteration nB) — fenced so it stays here
        const unsigned wB0 = adjr0[(size_t)nB * NN];
        const unsigned wB1 = adjr1[(size_t)nB * NN];
        const half8 bB0 = *(const half8*)(hb + nB * 4096);
        const half8 bB1 = *(const half8*)(hb + nB * 4096 + 512);
        const float4 dB0 = dst4[nB * 8], dB1 = dst4[nB * 8 + 1];
        __builtin_amdgcn_sched_barrier(0);

        COMPUTE(wA0, wA1, bA0, bA1, dA0, dA1);       // iter 2p, B-loads in flight
        __builtin_amdgcn_sched_barrier(0);

        if (p < 7) {                                  // prefetch buffer A (iter 2p+2)
            const int nA = 2 * p + 2;
            wA0 = adjr0[(size_t)nA * NN];
            wA1 = adjr1[(size_t)nA * NN];
            bA0 = *(const half8*)(hb + nA * 4096);
            bA1 = *(const half8*)(hb + nA * 4096 + 512);
            dA0 = dst4[nA * 8]; dA1 = dst4[nA * 8 + 1];
        }
        __builtin_amdgcn_sched_barrier(0);

        COMPUTE(wB0, wB1, bB0, bB1, dB0, dB1);       // iter 2p+1, A-loads in flight
        __builtin_amdgcn_sched_barrier(0);
    }

    // direct store of both frags (verified layout: i = 4g+r, d = r16); P now f16
    const size_t prow0 = (size_t)(jq * BB + b) * NN + i0;
#pragma unroll
    for (int r = 0; r < 4; ++r) {
        const size_t row0 = prow0 + 4 * g + r;
        const size_t row1 = prow0 + 16 + 4 * g + r;
        P[row0 * HID + h * 32 + r16]      = (_Float16)acc00[r];
        P[row0 * HID + h * 32 + 16 + r16] = (_Float16)acc01[r];
        P[row1 * HID + h * 32 + r16]      = (_Float16)acc10[r];
        P[row1 * HID + h * 32 + 16 + r16] = (_Float16)acc11[r];
        if (r16 == 0) {
            S[row0 * HEADS + h] = accS0[r];
            S[row1 * HEADS + h] = accS1[r];
        }
    }
}

// ---------------- k_proj: combine 4 f16 partials + projection (W^T in LDS) --------------
__global__ __launch_bounds__(256) void k_proj(
    const _Float16* __restrict__ P, const float* __restrict__ S,
    const float* __restrict__ W_out, float* __restrict__ dout)
{
    __shared__ float wlT[NQ][260];     // 16.6 KB
    __shared__ float red[256];

    const int t = threadIdx.x;
    const int k0 = blockIdx.x * 256;

#pragma unroll
    for (int u = 0; u < 4; ++u) {
        const int flat = (u * 256 + t) * 4;
        const float4 wv = *(const float4*)(W_out + (size_t)k0 * NQ + flat);
        const int krel = flat >> 4;
        const int q0 = flat & 15;
        wlT[q0 + 0][krel] = wv.x;
        wlT[q0 + 1][krel] = wv.y;
        wlT[q0 + 2][krel] = wv.z;
        wlT[q0 + 3][krel] = wv.w;
    }
    __syncthreads();

    const int q = t & 15;
    const int b = (t >> 4) & 3;
    const int ks = (t >> 6) * 64;
    const int i = (k0 + ks) >> 7;

    const _Float16* p0 = P + (size_t)(0 * BB + b) * KTOT + k0 + ks;
    const _Float16* p1 = P + (size_t)(1 * BB + b) * KTOT + k0 + ks;
    const _Float16* p2 = P + (size_t)(2 * BB + b) * KTOT + k0 + ks;
    const _Float16* p3 = P + (size_t)(3 * BB + b) * KTOT + k0 + ks;

    float acc = 0.f;
#pragma unroll
    for (int seg = 0; seg < 2; ++seg) {
        const int h = ((k0 + ks + seg * 32) >> 5) & 3;
        float rs = 0.f;
#pragma unroll
        for (int s = 0; s < NSL; ++s)
            rs += S[((size_t)(s * BB + b) * NN + i) * HEADS + h];
        const float inv = __builtin_amdgcn_rcpf(rs);
#pragma unroll
        for (int k8 = 0; k8 < 4; ++k8) {
            const int kk = seg * 32 + k8 * 8;
            const half8 a0 = *(const half8*)(p0 + kk);
            const half8 a1 = *(const half8*)(p1 + kk);
            const half8 a2 = *(const half8*)(p2 + kk);
            const half8 a3 = *(const half8*)(p3 + kk);
            const float4 w0 = *(const float4*)&wlT[q][ks + kk];
            const float4 w1 = *(const float4*)&wlT[q][ks + kk + 4];
            const float wf[8] = {w0.x, w0.y, w0.z, w0.w, w1.x, w1.y, w1.z, w1.w};
#pragma unroll
            for (int e = 0; e < 8; ++e) {
                const float ev = ((float)a0[e] + (float)a1[e]) + ((float)a2[e] + (float)a3[e]);
                acc = fmaf(ev * inv, wf[e], acc);
            }
        }
    }

    red[t] = acc;
    __syncthreads();
    if (t < 64)
        atomicAdd(&dout[t], red[t] + red[t + 64] + red[t + 128] + red[t + 192]);
}

extern "C" void kernel_launch(void* const* d_in, const int* in_sizes, int n_in,
                              void* d_out, int out_size, void* d_ws, size_t ws_size,
                              hipStream_t stream)
{
    const float* x       = (const float*)d_in[0];
    const int*   adj     = (const int*)d_in[1];
    const float* W_in    = (const float*)d_in[2];
    const float* b_in    = (const float*)d_in[3];
    const float* att_src = (const float*)d_in[4];
    const float* att_dst = (const float*)d_in[5];
    const float* W_out   = (const float*)d_in[6];
    const float* b_out   = (const float*)d_in[7];
    float* out = (float*)d_out;

    char* ws = (char*)d_ws;
    _Float16* P = (_Float16*)ws;                                     // NSL*BB*KTOT f16 = 8.4 MB
    float* S    = (float*)(ws + sizeof(_Float16) * (size_t)NSL * BB * KTOT);  // 512 KB
    float* srcA = S + (size_t)NSL * BB * NN * HEADS;                 // 128 KB
    float* dstA = srcA + (size_t)BB * HEADS * NN;                    // 128 KB
    _Float16* hHT = (_Float16*)(dstA + (size_t)BB * HEADS * NN);     // 2 MB (tiled)
    unsigned* adjT = (unsigned*)((char*)hHT + sizeof(_Float16) * (size_t)BB * KTOT); // 512 KB

    k_pre<<<HB + AB, 256, 0, stream>>>(x, W_in, b_in, att_src, att_dst, adj,
                                       hHT, srcA, dstA, adjT, b_out, out);
    // block = (iq 64, b 4, jq 4) -> 1024 blocks x 4 waves
    k_attn<<<NSL * BB * (NN / 32), 256, 0, stream>>>(adjT, hHT, srcA, dstA, P, S);
    k_proj<<<KTOT / 256, 256, 0, stream>>>(P, S, W_out, out);
}